// Round 1
// baseline (131.034 us; speedup 1.0000x reference)
//
#include <hip/hip_runtime.h>
#include <hip/hip_bf16.h>

// PositionalBias: pbv[n,j,h,d] = sum_{l=1..2046} w[h,|j-l|] * v[n,l,h,d]  (j in 1..2046, else 0)
//                 z_pb[l,h]    = sum_{j=1..2046} w[h,|l-j|]               (l in 1..2046, else 0)
// B=4, S=2048, H=12, D=64. Outputs fp32: pbv (6291456) then z_pb (24576).

typedef short short8 __attribute__((ext_vector_type(8)));   // 8 x bf16 bits (4 VGPRs)
typedef float floatx4 __attribute__((ext_vector_type(4)));  // MFMA accumulator

typedef const __attribute__((address_space(1))) void gvoid_t;
typedef __attribute__((address_space(3))) void lvoid_t;

__device__ __forceinline__ unsigned short f2bf(float f) {
  union { __hip_bfloat16 b; unsigned short u; } cv;
  cv.b = __float2bfloat16(f);  // RNE
  return cv.u;
}

// ---------------- v transpose: v[n][l][h][d] fp32 -> vb[h][n*64+d][l] bf16, zero l=0,2047 ---------
__global__ __launch_bounds__(256) void transpose_kernel(const float* __restrict__ v,
                                                        unsigned short* __restrict__ vb) {
  __shared__ float tile[64][65];
  const int lt = blockIdx.x;   // 32 tiles of 64 l
  const int h  = blockIdx.y;   // 12
  const int n  = blockIdx.z;   // 4
  const int tid = threadIdx.x;
  const int l0 = lt * 64;
  {
    const int d  = tid & 63;
    const int r0 = tid >> 6;           // 0..3
    #pragma unroll
    for (int rr = 0; rr < 16; ++rr) {
      int ll = r0 * 16 + rr;
      tile[ll][d] = v[(((size_t)n * 2048 + (l0 + ll)) * 12 + h) * 64 + d];
    }
  }
  __syncthreads();
  {
    const int d = tid >> 2;            // 0..63
    const int q = tid & 3;             // 0..3 (16 l each)
    unsigned short buf[16] __attribute__((aligned(16)));
    #pragma unroll
    for (int jj = 0; jj < 16; ++jj) {
      int l = l0 + q * 16 + jj;
      float f = tile[q * 16 + jj][d];
      buf[jj] = (l == 0 || l == 2047) ? (unsigned short)0 : f2bf(f);
    }
    unsigned short* dst = vb + ((size_t)h * 256 + n * 64 + d) * 2048 + l0 + q * 16;
    *(uint4*)dst       = *(const uint4*)&buf[0];
    *(uint4*)(dst + 8) = *(const uint4*)&buf[8];
  }
}

// ---------------- z_pb via prefix sums: z[i+1] = P[i] + P[2045-i] - w[h,0] -----------------------
__global__ __launch_bounds__(256) void zpb_kernel(const float* __restrict__ w,
                                                  float* __restrict__ zout) {
  __shared__ float wv[2048];
  __shared__ float part[256];
  __shared__ float pfx[2048];
  const int h = blockIdx.x;
  const int tid = threadIdx.x;
  const float* wh = w + (size_t)h * 2048;
  for (int i = tid; i < 2048; i += 256) wv[i] = (i < 2046) ? wh[i] : 0.f;
  __syncthreads();
  float s = 0.f;
  #pragma unroll
  for (int k = 0; k < 8; ++k) s += wv[tid * 8 + k];
  part[tid] = s;
  __syncthreads();
  if (tid == 0) {
    float run = 0.f;
    for (int t = 0; t < 256; ++t) { float tmp = part[t]; part[t] = run; run += tmp; }
  }
  __syncthreads();
  float run = part[tid];
  #pragma unroll
  for (int k = 0; k < 8; ++k) { run += wv[tid * 8 + k]; pfx[tid * 8 + k] = run; }
  __syncthreads();
  for (int i = tid; i < 2046; i += 256) {
    float z = pfx[i] + pfx[2045 - i] - wv[0];
    zout[(size_t)(i + 1) * 12 + h] = z;
  }
  if (tid == 0) { zout[h] = 0.f; zout[(size_t)2047 * 12 + h] = 0.f; }
}

// ---------------- main Toeplitz GEMM: block 128(j) x 128(nd), K=2048, KT=64 ----------------------
__global__ __launch_bounds__(256, 2) void gemm_kernel(const float* __restrict__ w,
                                                      const unsigned short* __restrict__ vb,
                                                      float* __restrict__ out) {
  __shared__ short we[4112];          // bf16 bits: we[t + 2055] = w[h,|t|] (|t|<=2045 else 0)
  __shared__ short vt[2][128][32];    // bf16 v-tile: vt[s][nd_local][kk], k = l0 + s*32 + kk

  const int jt  = blockIdx.x;         // 16
  const int ndt = blockIdx.y;         // 2
  const int h   = blockIdx.z;         // 12
  const int tid = threadIdx.x;
  const int lane = tid & 63;
  const int wid  = tid >> 6;          // 4 waves: (wm, wn) in 2x2
  const int wm = wid >> 1, wn = wid & 1;
  const int lm = lane & 15, quad = lane >> 4;

  // build extended kernel table
  const float* wh = w + (size_t)h * 2048;
  for (int i = tid; i < 4112; i += 256) {
    int t = i - 2055;
    int a = t < 0 ? -t : t;
    float val = (a <= 2045) ? wh[a] : 0.f;
    we[i] = (short)f2bf(val);
  }
  __syncthreads();

  const int nd0 = ndt * 128;
  const int jw  = jt * 128 + wm * 64;       // wave's j base
  const int ndw = nd0 + wn * 64;            // wave's nd base
  const unsigned short* vbp = vb + (size_t)h * 256 * 2048;

  floatx4 acc[4][4];
  #pragma unroll
  for (int ma = 0; ma < 4; ++ma)
    #pragma unroll
    for (int na = 0; na < 4; ++na)
      acc[ma][na] = (floatx4){0.f, 0.f, 0.f, 0.f};

  // A-frag loader: frag q covers diagonal offset (q-2)*16; value[lane][i] = we[j - l + 2055]
  auto load_af = [&](int q, int l0) -> short8 {
    int base = jw + (q - 2) * 16 + lm - (l0 + quad * 8) + 2055;
    short8 r;
    #pragma unroll
    for (int i = 0; i < 8; ++i) r[i] = we[base - i];
    return r;
  };

  short8 a4 = load_af(4, 0);
  short8 a5 = load_af(5, 0);

  #pragma unroll 1
  for (int l0 = 0; l0 < 2048; l0 += 64) {
    // stage v tile: 2 sub-tiles of 128 rows x 32 k (64B/row), 8 instrs each, 4 per wave
    #pragma unroll
    for (int s = 0; s < 2; ++s) {
      #pragma unroll
      for (int u = 0; u < 2; ++u) {
        int e  = wid * 2 + u;          // 0..7
        int r0 = e * 16;
        int grow = nd0 + r0 + (lane >> 2);
        int gcol = l0 + s * 32 + (lane & 3) * 8;
        const unsigned short* g = vbp + (size_t)grow * 2048 + gcol;
        __builtin_amdgcn_global_load_lds((gvoid_t*)g, (lvoid_t*)&vt[s][r0][0], 16, 0, 0);
      }
    }
    asm volatile("s_waitcnt vmcnt(0)" ::: "memory");
    __syncthreads();

    // Toeplitz A-frags: 6 diagonals, 2 rolled from previous iteration
    short8 afr[6];
    #pragma unroll
    for (int q = 0; q < 4; ++q) afr[q] = load_af(q, l0);
    afr[4] = a4; afr[5] = a5;
    a4 = afr[0]; a5 = afr[1];

    #pragma unroll
    for (int kc = 0; kc < 2; ++kc) {
      short8 bfr[4];
      #pragma unroll
      for (int na = 0; na < 4; ++na)
        bfr[na] = *(const short8*)&vt[kc][wn * 64 + na * 16 + lm][quad * 8];
      #pragma unroll
      for (int ma = 0; ma < 4; ++ma) {
        short8 af = afr[kc ? ma : ma + 2];
        #pragma unroll
        for (int na = 0; na < 4; ++na)
          acc[ma][na] = __builtin_amdgcn_mfma_f32_16x16x32_bf16(af, bfr[na], acc[ma][na], 0, 0, 0);
      }
    }
    __syncthreads();
  }

  // epilogue: D row = quad*4 + r (j), col = lm (nd); zero rows j=0 and j=2047
  #pragma unroll
  for (int ma = 0; ma < 4; ++ma) {
    #pragma unroll
    for (int na = 0; na < 4; ++na) {
      floatx4 c = acc[ma][na];
      int ndv = ndw + na * 16 + lm;
      int n = ndv >> 6, d = ndv & 63;
      #pragma unroll
      for (int r = 0; r < 4; ++r) {
        int j = jw + ma * 16 + quad * 4 + r;
        float val = (j == 0 || j == 2047) ? 0.f : c[r];
        out[(size_t)n * 1572864 + (size_t)j * 768 + h * 64 + d] = val;
      }
    }
  }
}

extern "C" void kernel_launch(void* const* d_in, const int* in_sizes, int n_in,
                              void* d_out, int out_size, void* d_ws, size_t ws_size,
                              hipStream_t stream) {
  const float* v = (const float*)d_in[0];   // (4,2048,12,64) fp32
  const float* w = (const float*)d_in[1];   // (12,2048) fp32
  float* out = (float*)d_out;               // pbv (6291456) + z_pb (24576) fp32
  unsigned short* vb = (unsigned short*)d_ws;  // 12*256*2048 bf16 = 12.58 MB

  transpose_kernel<<<dim3(32, 12, 4), 256, 0, stream>>>(v, vb);
  zpb_kernel<<<dim3(12), 256, 0, stream>>>(w, out + 6291456);
  gemm_kernel<<<dim3(16, 2, 12), 256, 0, stream>>>(w, vb, out);
}

// Round 2
// 126.480 us; speedup vs baseline: 1.0360x; 1.0360x over previous
//
#include <hip/hip_runtime.h>
#include <hip/hip_bf16.h>

// PositionalBias: pbv[n,j,h,d] = sum_{l=1..2046} w[h,|j-l|] * v[n,l,h,d]  (j in 1..2046, else 0)
//                 z_pb[l,h]    = sum_{j=1..2046} w[h,|l-j|]               (l in 1..2046, else 0)
// B=4, S=2048, H=12, D=64. Outputs fp32: pbv (6291456) then z_pb (24576).

typedef short short8 __attribute__((ext_vector_type(8)));   // 8 x bf16 bits (4 VGPRs)
typedef float floatx4 __attribute__((ext_vector_type(4)));  // MFMA accumulator

typedef const __attribute__((address_space(1))) void gvoid_t;
typedef __attribute__((address_space(3))) void lvoid_t;

__device__ __forceinline__ unsigned short f2bf(float f) {
  union { __hip_bfloat16 b; unsigned short u; } cv;
  cv.b = __float2bfloat16(f);  // RNE
  return cv.u;
}

// ---------------- v transpose: v[n][l][h][d] fp32 -> vb[h][n*64+d][l] bf16, zero l=0,2047 ---------
__global__ __launch_bounds__(256) void transpose_kernel(const float* __restrict__ v,
                                                        unsigned short* __restrict__ vb) {
  __shared__ float tile[64][65];
  const int lt = blockIdx.x;   // 32 tiles of 64 l
  const int h  = blockIdx.y;   // 12
  const int n  = blockIdx.z;   // 4
  const int tid = threadIdx.x;
  const int l0 = lt * 64;
  {
    const int d  = tid & 63;
    const int r0 = tid >> 6;           // 0..3
    #pragma unroll
    for (int rr = 0; rr < 16; ++rr) {
      int ll = r0 * 16 + rr;
      tile[ll][d] = v[(((size_t)n * 2048 + (l0 + ll)) * 12 + h) * 64 + d];
    }
  }
  __syncthreads();
  {
    const int d = tid >> 2;            // 0..63
    const int q = tid & 3;             // 0..3 (16 l each)
    unsigned short buf[16] __attribute__((aligned(16)));
    #pragma unroll
    for (int jj = 0; jj < 16; ++jj) {
      int l = l0 + q * 16 + jj;
      float f = tile[q * 16 + jj][d];
      buf[jj] = (l == 0 || l == 2047) ? (unsigned short)0 : f2bf(f);
    }
    unsigned short* dst = vb + ((size_t)h * 256 + n * 64 + d) * 2048 + l0 + q * 16;
    *(uint4*)dst       = *(const uint4*)&buf[0];
    *(uint4*)(dst + 8) = *(const uint4*)&buf[8];
  }
}

// ---------------- z_pb via prefix sums: z[i+1] = P[i] + P[2045-i] - w[h,0] -----------------------
__global__ __launch_bounds__(256) void zpb_kernel(const float* __restrict__ w,
                                                  float* __restrict__ zout) {
  __shared__ float wv[2048];
  __shared__ float pfx[2048];
  __shared__ float wsum[4];
  const int h = blockIdx.x;
  const int tid = threadIdx.x;
  const float* wh = w + (size_t)h * 2048;
  for (int i = tid; i < 2048; i += 256) wv[i] = (i < 2046) ? wh[i] : 0.f;
  __syncthreads();
  const int base = tid * 8;
  float run0 = 0.f;
  #pragma unroll
  for (int k = 0; k < 8; ++k) run0 += wv[base + k];
  // wave-level inclusive scan of thread sums
  float x = run0;
  #pragma unroll
  for (int d = 1; d < 64; d <<= 1) {
    float y = __shfl_up(x, d);
    if ((tid & 63) >= d) x += y;
  }
  if ((tid & 63) == 63) wsum[tid >> 6] = x;
  __syncthreads();
  const int wid = tid >> 6;
  float woff = 0.f;
  #pragma unroll
  for (int u = 0; u < 3; ++u) { float t = wsum[u]; if (u < wid) woff += t; }
  float excl = x + woff - run0;   // exclusive prefix over thread sums
  float pr = excl;
  #pragma unroll
  for (int k = 0; k < 8; ++k) { pr += wv[base + k]; pfx[base + k] = pr; }
  __syncthreads();
  for (int i = tid; i < 2046; i += 256) {
    float z = pfx[i] + pfx[2045 - i] - wv[0];
    zout[(size_t)(i + 1) * 12 + h] = z;
  }
  if (tid == 0) { zout[h] = 0.f; zout[(size_t)2047 * 12 + h] = 0.f; }
}

// ---------------- main Toeplitz GEMM: block 128(j) x 128(nd), K=2048, KT=64 ----------------------
// A-fragment trick: reversed table (ascending in k) stored in 8 pre-shifted copies so every
// lane's 8 consecutive bf16 A-values are one aligned ds_read_b128.
//   T_c[p] = w_ext[127 + jb - p - c],  lane uses copy c = (7 - lm) & 7, reads at p0 - c (8-aligned).
__global__ __launch_bounds__(256, 2) void gemm_kernel(const float* __restrict__ w,
                                                      const unsigned short* __restrict__ vb,
                                                      float* __restrict__ out) {
  __shared__ __attribute__((aligned(16))) short Tls[8 * 2184];  // 8 shifted copies, 34.9 KB
  __shared__ __attribute__((aligned(16))) short vt[2][128][32]; // bf16 v-tile, 16.4 KB

  const int jt  = blockIdx.x;         // 16
  const int ndt = blockIdx.y;         // 2
  const int h   = blockIdx.z;         // 12
  const int tid = threadIdx.x;
  const int lane = tid & 63;
  const int wid  = tid >> 6;          // 4 waves: (wm, wn) in 2x2
  const int wm = wid >> 1, wn = wid & 1;
  const int lm = lane & 15, quad = lane >> 4;
  const int jb = jt * 128;

  // build reversed, 8x-shifted kernel table (vectorized b128 stores; 2184 = 273*8)
  const float* wh = w + (size_t)h * 2048;
  for (int g = tid; g < 8 * 273; g += 256) {
    int c  = g / 273;
    int p8 = (g - c * 273) * 8;
    unsigned short buf[8] __attribute__((aligned(16)));
    #pragma unroll
    for (int i = 0; i < 8; ++i) {
      int t = 127 + jb - (p8 + i) - c;
      int a = t < 0 ? -t : t;
      buf[i] = (a <= 2045) ? f2bf(wh[a]) : (unsigned short)0;
    }
    *(short8*)&Tls[c * 2184 + p8] = *(const short8*)buf;
  }
  __syncthreads();

  const int nd0 = ndt * 128;
  const int jw  = jb + wm * 64;             // wave's j base
  const int ndw = nd0 + wn * 64;            // wave's nd base
  const unsigned short* vbp = vb + (size_t)h * 256 * 2048;

  floatx4 acc[4][4];
  #pragma unroll
  for (int ma = 0; ma < 4; ++ma)
    #pragma unroll
    for (int na = 0; na < 4; ++na)
      acc[ma][na] = (floatx4){0.f, 0.f, 0.f, 0.f};

  // A-frag: value[i] = w_ext[j - l], j = jw + ma*16 + lm, l = l0 + kc*32 + quad*8 + i
  // p0 = l0 + 16*g + 127 + quad*8 - wm*64 - lm, g = 2*kc - ma; one aligned b128 from copy (p0&7).
  const int pbase = 127 + quad * 8 - wm * 64 - lm;
  auto load_af = [&](int g16, int l0) -> short8 {
    int p0 = l0 + g16 + pbase;
    int c  = p0 & 7;
    return *(const short8*)&Tls[c * 2184 + (p0 - c)];
  };

  short8 a4 = load_af(-48, 0);   // g=-3 preload
  short8 a5 = load_af(-32, 0);   // g=-2 preload

  #pragma unroll 1
  for (int l0 = 0; l0 < 2048; l0 += 64) {
    // stage v tile: 2 sub-tiles of 128 rows x 32 k (64B/row), 8 dma instrs each, 4 per wave
    #pragma unroll
    for (int s = 0; s < 2; ++s) {
      #pragma unroll
      for (int u = 0; u < 2; ++u) {
        int e  = wid * 2 + u;          // 0..7
        int r0 = e * 16;
        int grow = nd0 + r0 + (lane >> 2);
        int gcol = l0 + s * 32 + (lane & 3) * 8;
        const unsigned short* g = vbp + (size_t)grow * 2048 + gcol;
        __builtin_amdgcn_global_load_lds((gvoid_t*)g, (lvoid_t*)&vt[s][r0][0], 16, 0, 0);
      }
    }
    asm volatile("s_waitcnt vmcnt(0)" ::: "memory");
    __syncthreads();

    // Toeplitz A-frags: 6 diagonals g=-3..2 (index u=g+3), roll 2 across iterations
    short8 afr[6];
    afr[0] = a4; afr[1] = a5;
    afr[2] = load_af(-16, l0);
    afr[3] = load_af(0,   l0);
    afr[4] = load_af(16,  l0);
    afr[5] = load_af(32,  l0);
    a4 = afr[4]; a5 = afr[5];

    #pragma unroll
    for (int kc = 0; kc < 2; ++kc) {
      short8 bfr[4];
      #pragma unroll
      for (int na = 0; na < 4; ++na)
        bfr[na] = *(const short8*)&vt[kc][wn * 64 + na * 16 + lm][quad * 8];
      #pragma unroll
      for (int ma = 0; ma < 4; ++ma) {
        short8 af = afr[(kc ? 5 : 3) - ma];   // u = 2*kc - ma + 3
        #pragma unroll
        for (int na = 0; na < 4; ++na)
          acc[ma][na] = __builtin_amdgcn_mfma_f32_16x16x32_bf16(af, bfr[na], acc[ma][na], 0, 0, 0);
      }
    }
    __syncthreads();
  }

  // epilogue: D row = quad*4 + r (j), col = lm (nd); zero rows j=0 and j=2047
  #pragma unroll
  for (int ma = 0; ma < 4; ++ma) {
    #pragma unroll
    for (int na = 0; na < 4; ++na) {
      floatx4 c = acc[ma][na];
      int ndv = ndw + na * 16 + lm;
      int n = ndv >> 6, d = ndv & 63;
      #pragma unroll
      for (int r = 0; r < 4; ++r) {
        int j = jw + ma * 16 + quad * 4 + r;
        float val = (j == 0 || j == 2047) ? 0.f : c[r];
        out[(size_t)n * 1572864 + (size_t)j * 768 + h * 64 + d] = val;
      }
    }
  }
}

extern "C" void kernel_launch(void* const* d_in, const int* in_sizes, int n_in,
                              void* d_out, int out_size, void* d_ws, size_t ws_size,
                              hipStream_t stream) {
  const float* v = (const float*)d_in[0];   // (4,2048,12,64) fp32
  const float* w = (const float*)d_in[1];   // (12,2048) fp32
  float* out = (float*)d_out;               // pbv (6291456) + z_pb (24576) fp32
  unsigned short* vb = (unsigned short*)d_ws;  // 12*256*2048 bf16 = 12.58 MB

  transpose_kernel<<<dim3(32, 12, 4), 256, 0, stream>>>(v, vb);
  zpb_kernel<<<dim3(12), 256, 0, stream>>>(w, out + 6291456);
  gemm_kernel<<<dim3(16, 2, 12), 256, 0, stream>>>(w, vb, out);
}

// Round 3
// 123.652 us; speedup vs baseline: 1.0597x; 1.0229x over previous
//
#include <hip/hip_runtime.h>
#include <hip/hip_bf16.h>

// PositionalBias: pbv[n,j,h,d] = sum_{l=1..2046} w[h,|j-l|] * v[n,l,h,d]  (j in 1..2046, else 0)
//                 z_pb[l,h]    = sum_{j=1..2046} w[h,|l-j|]               (l in 1..2046, else 0)
// B=4, S=2048, H=12, D=64. Outputs fp32: pbv (6291456) then z_pb (24576).

typedef short short8 __attribute__((ext_vector_type(8)));   // 8 x bf16 bits (4 VGPRs)
typedef float floatx4 __attribute__((ext_vector_type(4)));  // MFMA accumulator

typedef const __attribute__((address_space(1))) void gvoid_t;
typedef __attribute__((address_space(3))) void lvoid_t;

__device__ __forceinline__ unsigned short f2bf(float f) {
  union { __hip_bfloat16 b; unsigned short u; } cv;
  cv.b = __float2bfloat16(f);  // RNE
  return cv.u;
}

// ---------------- prep: v transpose (+ zpb in extra blocks) -------------------------------------
// vb[h][nd][l] bf16, zero l=0,2047, with k-chunk xor swizzle: within each 64-l tile,
// chunk (8 shorts) c stored at slot c ^ (nd & 7)  -> gemm's contiguous DMA lands a
// bank-conflict-free LDS layout (padding is impossible with global_load_lds).
__global__ __launch_bounds__(256) void prep_kernel(const float* __restrict__ v,
                                                   const float* __restrict__ w,
                                                   unsigned short* __restrict__ vb,
                                                   float* __restrict__ zout) {
  __shared__ float smem[64 * 65];
  const int lt = blockIdx.x;   // 0..32; 32 => zpb block
  const int h  = blockIdx.y;   // 12
  const int n  = blockIdx.z;   // 4
  const int tid = threadIdx.x;

  if (lt == 32) {               // ---- zpb: z[i+1] = P[i] + P[2045-i] - w[h,0] ----
    if (n != 0) return;
    float* wv  = smem;          // [2048]
    float* pfx = smem + 2048;   // [2048]
    __shared__ float wsum[4];
    const float* wh = w + (size_t)h * 2048;
    for (int i = tid; i < 2048; i += 256) wv[i] = (i < 2046) ? wh[i] : 0.f;
    __syncthreads();
    const int base = tid * 8;
    float run0 = 0.f;
    #pragma unroll
    for (int k = 0; k < 8; ++k) run0 += wv[base + k];
    float x = run0;
    #pragma unroll
    for (int d = 1; d < 64; d <<= 1) {
      float y = __shfl_up(x, d);
      if ((tid & 63) >= d) x += y;
    }
    if ((tid & 63) == 63) wsum[tid >> 6] = x;
    __syncthreads();
    const int wid = tid >> 6;
    float woff = 0.f;
    #pragma unroll
    for (int u = 0; u < 3; ++u) { float t = wsum[u]; if (u < wid) woff += t; }
    float pr = x + woff - run0;
    #pragma unroll
    for (int k = 0; k < 8; ++k) { pr += wv[base + k]; pfx[base + k] = pr; }
    __syncthreads();
    for (int i = tid; i < 2046; i += 256) {
      float z = pfx[i] + pfx[2045 - i] - wv[0];
      zout[(size_t)(i + 1) * 12 + h] = z;
    }
    if (tid == 0) { zout[h] = 0.f; zout[(size_t)2047 * 12 + h] = 0.f; }
    return;
  }

  // ---- transpose tile ----
  float (*tile)[65] = (float(*)[65])smem;
  const int l0 = lt * 64;
  {
    const int d  = tid & 63;
    const int r0 = tid >> 6;           // 0..3
    #pragma unroll
    for (int rr = 0; rr < 16; ++rr) {
      int ll = r0 * 16 + rr;
      tile[ll][d] = v[(((size_t)n * 2048 + (l0 + ll)) * 12 + h) * 64 + d];
    }
  }
  __syncthreads();
  {
    const int d = tid >> 2;            // 0..63
    const int q = tid & 3;             // 0..3 (16 l each)
    const int nd = n * 64 + d;
    const int sw = nd & 7;
    unsigned short buf[16] __attribute__((aligned(16)));
    #pragma unroll
    for (int jj = 0; jj < 16; ++jj) {
      int l = l0 + q * 16 + jj;
      float f = tile[q * 16 + jj][d];
      buf[jj] = (l == 0 || l == 2047) ? (unsigned short)0 : f2bf(f);
    }
    unsigned short* dstrow = vb + ((size_t)h * 256 + nd) * 2048 + l0;
    int c0 = (2 * q) ^ sw, c1 = (2 * q + 1) ^ sw;
    *(uint4*)(dstrow + c0 * 8) = *(const uint4*)&buf[0];
    *(uint4*)(dstrow + c1 * 8) = *(const uint4*)&buf[8];
  }
}

// ---------------- main Toeplitz GEMM: block 128(j) x 64(nd), K=2048, KT=64, pipelined -----------
// grid 16 x 4 x 12 = 768 blocks = exactly 3/CU (LDS 51.3 KB). Double-buffered vt with DMA
// prefetch issued before compute -> memory latency overlapped.
__global__ __launch_bounds__(256, 3) void gemm_kernel(const float* __restrict__ w,
                                                      const unsigned short* __restrict__ vb,
                                                      float* __restrict__ out) {
  __shared__ __attribute__((aligned(16))) short Tls[8 * 2184];  // 8 shifted copies, 34.9 KB
  __shared__ __attribute__((aligned(16))) short vt[2][64][64];  // double-buffered v tile, 16.4 KB

  const int jt  = blockIdx.x;         // 16
  const int ndt = blockIdx.y;         // 4
  const int h   = blockIdx.z;         // 12
  const int tid = threadIdx.x;
  const int lane = tid & 63;
  const int wid  = tid >> 6;          // 4 waves: wm = j-half, wn = nd-half
  const int wm = wid >> 1, wn = wid & 1;
  const int lm = lane & 15, quad = lane >> 4;
  const int jb = jt * 128;
  const int nd0 = ndt * 64;
  const unsigned short* vbp = vb + (size_t)h * 256 * 2048;

  // DMA one KT=64 tile (64 rows x 128 B) into vt[b]; 2 instrs/wave, verbatim (swizzle pre-baked in vb)
  auto issue_dma = [&](int l0, int b) {
    #pragma unroll
    for (int u = 0; u < 2; ++u) {
      int e = wid * 2 + u;             // 0..7, 8 rows each
      const unsigned short* g = vbp + (size_t)(nd0 + e * 8 + (lane >> 3)) * 2048 + l0 + (lane & 7) * 8;
      __builtin_amdgcn_global_load_lds((gvoid_t*)g, (lvoid_t*)&vt[b][e * 8][0], 16, 0, 0);
    }
  };

  issue_dma(0, 0);   // overlap first tile's latency with table build

  // build reversed, 8x-shifted kernel table (2184 = 273*8): T_c[p] = w_ext[127 + jb - p - c]
  const float* wh = w + (size_t)h * 2048;
  for (int g = tid; g < 8 * 273; g += 256) {
    int c  = g / 273;
    int p8 = (g - c * 273) * 8;
    unsigned short buf[8] __attribute__((aligned(16)));
    #pragma unroll
    for (int i = 0; i < 8; ++i) {
      int t = 127 + jb - (p8 + i) - c;
      int a = t < 0 ? -t : t;
      buf[i] = (a <= 2045) ? f2bf(wh[a]) : (unsigned short)0;
    }
    *(short8*)&Tls[c * 2184 + p8] = *(const short8*)buf;
  }
  __syncthreads();

  floatx4 acc[4][2];
  #pragma unroll
  for (int ma = 0; ma < 4; ++ma)
    #pragma unroll
    for (int na = 0; na < 2; ++na)
      acc[ma][na] = (floatx4){0.f, 0.f, 0.f, 0.f};

  // A-frag: value[i] = w_ext[j - l], j = jb + wm*64 + ma*16 + lm, l = l0 + kc*32 + quad*8 + i
  // g = 2*kc - ma; one aligned ds_read_b128 from shifted copy (p0 & 7).
  const int pbase = 127 + quad * 8 - wm * 64 - lm;
  auto load_af = [&](int g16, int l0) -> short8 {
    int p0 = l0 + g16 + pbase;
    int c  = p0 & 7;
    return *(const short8*)&Tls[c * 2184 + (p0 - c)];
  };

  short8 a4 = load_af(-48, 0);   // g=-3 preload
  short8 a5 = load_af(-32, 0);   // g=-2 preload

  #pragma unroll 2
  for (int t = 0; t < 32; ++t) {
    const int l0 = t * 64;
    const int b  = t & 1;
    // fresh A-frags issue before the DMA wait (Tls is stable; overlaps latency)
    short8 afr[6];
    afr[0] = a4; afr[1] = a5;
    afr[2] = load_af(-16, l0);
    afr[3] = load_af(0,   l0);
    afr[4] = load_af(16,  l0);
    afr[5] = load_af(32,  l0);
    a4 = afr[4]; a5 = afr[5];

    asm volatile("s_waitcnt vmcnt(0)" ::: "memory");  // tile t arrived (own-wave DMAs)
    __syncthreads();                                   // all waves' DMAs visible
    if (t < 31) issue_dma(l0 + 64, b ^ 1);             // prefetch flies during compute

    #pragma unroll
    for (int kc = 0; kc < 2; ++kc) {
      short8 bfr[2];
      #pragma unroll
      for (int na = 0; na < 2; ++na) {
        int row  = wn * 32 + na * 16 + lm;
        int slot = (kc * 4 + quad) ^ (lm & 7);         // undo vb xor-swizzle (row&7 == lm&7)
        bfr[na] = *(const short8*)&vt[b][row][slot * 8];
      }
      #pragma unroll
      for (int ma = 0; ma < 4; ++ma) {
        short8 af = afr[(kc ? 5 : 3) - ma];            // g = 2*kc - ma
        #pragma unroll
        for (int na = 0; na < 2; ++na)
          acc[ma][na] = __builtin_amdgcn_mfma_f32_16x16x32_bf16(af, bfr[na], acc[ma][na], 0, 0, 0);
      }
    }
  }

  // epilogue: D row = quad*4 + r (j), col = lm (nd); zero rows j=0 and j=2047
  const int jw  = jb + wm * 64;
  const int ndw = nd0 + wn * 32;
  #pragma unroll
  for (int ma = 0; ma < 4; ++ma) {
    #pragma unroll
    for (int na = 0; na < 2; ++na) {
      floatx4 c = acc[ma][na];
      int ndv = ndw + na * 16 + lm;
      int n = ndv >> 6, d = ndv & 63;
      #pragma unroll
      for (int r = 0; r < 4; ++r) {
        int j = jw + ma * 16 + quad * 4 + r;
        float val = (j == 0 || j == 2047) ? 0.f : c[r];
        out[(size_t)n * 1572864 + (size_t)j * 768 + h * 64 + d] = val;
      }
    }
  }
}

extern "C" void kernel_launch(void* const* d_in, const int* in_sizes, int n_in,
                              void* d_out, int out_size, void* d_ws, size_t ws_size,
                              hipStream_t stream) {
  const float* v = (const float*)d_in[0];   // (4,2048,12,64) fp32
  const float* w = (const float*)d_in[1];   // (12,2048) fp32
  float* out = (float*)d_out;               // pbv (6291456) + z_pb (24576) fp32
  unsigned short* vb = (unsigned short*)d_ws;  // 12*256*2048 bf16 = 12.58 MB

  prep_kernel<<<dim3(33, 12, 4), 256, 0, stream>>>(v, w, vb, out + 6291456);
  gemm_kernel<<<dim3(16, 4, 12), 256, 0, stream>>>(w, vb, out);
}